// Round 1
// baseline (1212.988 us; speedup 1.0000x reference)
//
#include <hip/hip_runtime.h>

// ---------- types & helpers ----------
typedef __bf16 bf16x8 __attribute__((ext_vector_type(8)));
typedef float  f32x4  __attribute__((ext_vector_type(4)));

__device__ __forceinline__ float bf2f(unsigned short h) {
    union { unsigned int u; float f; } c; c.u = ((unsigned int)h) << 16; return c.f;
}
// round-to-nearest-even fp32 -> bf16
__device__ __forceinline__ unsigned short f2bf(float x) {
    union { float f; unsigned int u; } c; c.f = x;
    unsigned int u = c.u + 0x7FFFu + ((c.u >> 16) & 1u);
    return (unsigned short)(u >> 16);
}

#define BM 128
#define BN 128
#define BK 32
#define AK 40   // padded LDS row stride in bf16 elems (80 B: 16B-aligned frags, 2-way banks = free)
#define NT 256

// ---------- split fp32 -> bf16 hi/lo planes ----------
__global__ void split_kernel(const float* __restrict__ x,
                             unsigned short* __restrict__ hi,
                             unsigned short* __restrict__ lo, int n) {
    for (int i = blockIdx.x * blockDim.x + threadIdx.x; i < n; i += gridDim.x * blockDim.x) {
        float v = x[i];
        unsigned short h = f2bf(v);
        hi[i] = h;
        if (lo) lo[i] = f2bf(v - bf2f(h));
    }
}

// ---------- unified GEMM ----------
// C[M,N] = A[M,K] * B(K,N view) (+bias)
// SPLIT:   true -> 3-MFMA split-bf16 product (needs hi+lo of both operands)
// A_MODE:  0 = A is fp32 global [m][k], convert to hi/lo during staging
//          1 = A is bf16 plane(s) [m][k]
// B_MODE:  0 = B is bf16 plane(s) [k][n]  (transpose-staged into LDS [n][k])
//          1 = B is bf16 plane(s) [n][k]  (direct)
// OUT:     0 = fp32, 1 = bf16, 2 = bf16 hi/lo planes
template<bool SPLIT, int A_MODE, int B_MODE, int OUT_MODE, bool BIAS>
__global__ __launch_bounds__(NT, 2)
void gemm_kernel(const float* __restrict__ A32,
                 const unsigned short* __restrict__ Aph,
                 const unsigned short* __restrict__ Apl,
                 const unsigned short* __restrict__ Bph,
                 const unsigned short* __restrict__ Bpl,
                 const float* __restrict__ bias,
                 float* __restrict__ Cf,
                 unsigned short* __restrict__ Chi,
                 unsigned short* __restrict__ Clo,
                 int M, int N, int K, int lda, int ldb, int ldc,
                 long long sA, long long sB, long long sC)
{
    __shared__ __align__(16) unsigned short AsH[BM * AK];
    __shared__ __align__(16) unsigned short AsL[BM * AK];
    __shared__ __align__(16) unsigned short BsH[BN * AK];
    __shared__ __align__(16) unsigned short BsL[BN * AK];
    __shared__ float biasS[BN];

    const int tid  = threadIdx.x;
    const int b    = blockIdx.z;
    const int m0   = blockIdx.y * BM;
    const int n0   = blockIdx.x * BN;
    const int lane = tid & 63;
    const int w    = tid >> 6;
    const int wm   = (w >> 1) * 64;
    const int wn   = (w & 1) * 64;
    const int l15  = lane & 15;
    const int quad = lane >> 4;

    if (BIAS && tid < BN) biasS[tid] = bias[n0 + tid];

    f32x4 acc[4][4];
    #pragma unroll
    for (int i = 0; i < 4; ++i)
        #pragma unroll
        for (int j = 0; j < 4; ++j)
            #pragma unroll
            for (int r = 0; r < 4; ++r) acc[i][j][r] = 0.0f;

    for (int k0 = 0; k0 < K; k0 += BK) {
        __syncthreads();
        // ---- stage A tile [BM][BK] ----
        if (A_MODE == 0) {
            const float* Ab = A32 + (long long)b * sA + (long long)m0 * lda + k0;
            #pragma unroll
            for (int p = 0; p < 4; ++p) {
                int idx = p * NT + tid;       // 0..1023
                int row = idx >> 3;           // 8 chunks of 4 floats per row
                int ch  = idx & 7;
                float4 v = *(const float4*)(Ab + (long long)row * lda + ch * 4);
                float vv[4] = {v.x, v.y, v.z, v.w};
                unsigned short h[4], l[4];
                #pragma unroll
                for (int e = 0; e < 4; ++e) {
                    h[e] = f2bf(vv[e]);
                    if (SPLIT) l[e] = f2bf(vv[e] - bf2f(h[e]));
                }
                int o = row * AK + ch * 4;
                *(unsigned int*)&AsH[o]     = (unsigned int)h[0] | ((unsigned int)h[1] << 16);
                *(unsigned int*)&AsH[o + 2] = (unsigned int)h[2] | ((unsigned int)h[3] << 16);
                if (SPLIT) {
                    *(unsigned int*)&AsL[o]     = (unsigned int)l[0] | ((unsigned int)l[1] << 16);
                    *(unsigned int*)&AsL[o + 2] = (unsigned int)l[2] | ((unsigned int)l[3] << 16);
                }
            }
        } else {
            const unsigned short* Ab = Aph + (long long)b * sA + (long long)m0 * lda + k0;
            #pragma unroll
            for (int p = 0; p < 2; ++p) {
                int idx = p * NT + tid;       // 0..511
                int row = idx >> 2;           // 4 chunks of 8 bf16 per row
                int ch  = idx & 3;
                *(uint4*)&AsH[row * AK + ch * 8] =
                    *(const uint4*)(Ab + (long long)row * lda + ch * 8);
            }
            if (SPLIT) {
                const unsigned short* Ab2 = Apl + (long long)b * sA + (long long)m0 * lda + k0;
                #pragma unroll
                for (int p = 0; p < 2; ++p) {
                    int idx = p * NT + tid;
                    int row = idx >> 2;
                    int ch  = idx & 3;
                    *(uint4*)&AsL[row * AK + ch * 8] =
                        *(const uint4*)(Ab2 + (long long)row * lda + ch * 8);
                }
            }
        }
        // ---- stage B tile into LDS as [n][k] ----
        if (B_MODE == 1) {
            const unsigned short* Bb = Bph + (long long)b * sB + (long long)n0 * ldb + k0;
            #pragma unroll
            for (int p = 0; p < 2; ++p) {
                int idx = p * NT + tid;
                int row = idx >> 2;
                int ch  = idx & 3;
                *(uint4*)&BsH[row * AK + ch * 8] =
                    *(const uint4*)(Bb + (long long)row * ldb + ch * 8);
            }
            if (SPLIT) {
                const unsigned short* Bb2 = Bpl + (long long)b * sB + (long long)n0 * ldb + k0;
                #pragma unroll
                for (int p = 0; p < 2; ++p) {
                    int idx = p * NT + tid;
                    int row = idx >> 2;
                    int ch  = idx & 3;
                    *(uint4*)&BsL[row * AK + ch * 8] =
                        *(const uint4*)(Bb2 + (long long)row * ldb + ch * 8);
                }
            }
        } else {
            // B global [k][n]; each thread gathers 8 k-values for one n, writes one 16B LDS row chunk
            const unsigned short* Bb = Bph + (long long)b * sB + (long long)k0 * ldb + n0;
            int n   = tid & 127;
            int kc0 = tid >> 7;               // 0..1
            #pragma unroll
            for (int p = 0; p < 2; ++p) {
                int kc = kc0 + p * 2;         // 0..3
                union { unsigned short u16[8]; uint4 v; } t;
                #pragma unroll
                for (int e = 0; e < 8; ++e)
                    t.u16[e] = Bb[(long long)(kc * 8 + e) * ldb + n];
                *(uint4*)&BsH[n * AK + kc * 8] = t.v;
            }
            if (SPLIT) {
                const unsigned short* Bb2 = Bpl + (long long)b * sB + (long long)k0 * ldb + n0;
                #pragma unroll
                for (int p = 0; p < 2; ++p) {
                    int kc = kc0 + p * 2;
                    union { unsigned short u16[8]; uint4 v; } t;
                    #pragma unroll
                    for (int e = 0; e < 8; ++e)
                        t.u16[e] = Bb2[(long long)(kc * 8 + e) * ldb + n];
                    *(uint4*)&BsL[n * AK + kc * 8] = t.v;
                }
            }
        }
        __syncthreads();

        // ---- MFMA ----
        bf16x8 ah[4], al[4], bh[4], bl[4];
        #pragma unroll
        for (int i = 0; i < 4; ++i) {
            int r = wm + i * 16 + l15;
            ah[i] = *(const bf16x8*)&AsH[r * AK + quad * 8];
            if (SPLIT) al[i] = *(const bf16x8*)&AsL[r * AK + quad * 8];
        }
        #pragma unroll
        for (int j = 0; j < 4; ++j) {
            int r = wn + j * 16 + l15;
            bh[j] = *(const bf16x8*)&BsH[r * AK + quad * 8];
            if (SPLIT) bl[j] = *(const bf16x8*)&BsL[r * AK + quad * 8];
        }
        #pragma unroll
        for (int i = 0; i < 4; ++i)
            #pragma unroll
            for (int j = 0; j < 4; ++j) {
                acc[i][j] = __builtin_amdgcn_mfma_f32_16x16x32_bf16(ah[i], bh[j], acc[i][j], 0, 0, 0);
                if (SPLIT) {
                    acc[i][j] = __builtin_amdgcn_mfma_f32_16x16x32_bf16(ah[i], bl[j], acc[i][j], 0, 0, 0);
                    acc[i][j] = __builtin_amdgcn_mfma_f32_16x16x32_bf16(al[i], bh[j], acc[i][j], 0, 0, 0);
                }
            }
    }

    // ---- epilogue (C/D layout: col=lane&15, row=quad*4+r; m89-verified) ----
    #pragma unroll
    for (int i = 0; i < 4; ++i)
        #pragma unroll
        for (int j = 0; j < 4; ++j)
            #pragma unroll
            for (int r = 0; r < 4; ++r) {
                int row = wm + i * 16 + quad * 4 + r;
                int col = wn + j * 16 + l15;
                float c = acc[i][j][r];
                if (BIAS) c += biasS[col];
                long long o = (long long)b * sC + (long long)(m0 + row) * ldc + (n0 + col);
                if (OUT_MODE == 0) {
                    Cf[o] = c;
                } else if (OUT_MODE == 1) {
                    Chi[o] = f2bf(c);
                } else {
                    unsigned short hh = f2bf(c);
                    Chi[o] = hh;
                    Clo[o] = f2bf(c - bf2f(hh));
                }
            }
}

// ---------- row softmax: S fp32 [8192][4096] -> P bf16 in-place (row stride 8192) ----------
__global__ void softmax_kernel(const float* __restrict__ S, unsigned short* __restrict__ P) {
    const int row = blockIdx.x;
    const int tid = threadIdx.x;
    const float* s = S + (long long)row * 4096;
    float v[16];
    float m = -3.4e38f;
    #pragma unroll
    for (int i = 0; i < 16; ++i) { v[i] = s[tid + i * 256]; m = fmaxf(m, v[i]); }
    __shared__ float red[256];
    red[tid] = m; __syncthreads();
    for (int st = 128; st > 0; st >>= 1) {
        if (tid < st) red[tid] = fmaxf(red[tid], red[tid + st]);
        __syncthreads();
    }
    m = red[0]; __syncthreads();
    float sum = 0.f;
    #pragma unroll
    for (int i = 0; i < 16; ++i) { v[i] = __expf(v[i] - m); sum += v[i]; }
    red[tid] = sum; __syncthreads();
    for (int st = 128; st > 0; st >>= 1) {
        if (tid < st) red[tid] += red[tid + st];
        __syncthreads();
    }
    const float scale = 0.03125f / red[0];   // 1/sqrt(1024) post-softmax scale folded in
    unsigned short* p = P + (long long)row * 8192;   // first half of the fp32 row slot
    #pragma unroll
    for (int i = 0; i < 16; ++i) p[tid + i * 256] = f2bf(v[i] * scale);
}

// ---------- launch ----------
extern "C" void kernel_launch(void* const* d_in, const int* in_sizes, int n_in,
                              void* d_out, int out_size, void* d_ws, size_t ws_size,
                              hipStream_t stream) {
    const float* query = (const float*)d_in[0];
    const float* ref   = (const float*)d_in[1];
    const float* Wq    = (const float*)d_in[2];
    const float* bq    = (const float*)d_in[3];
    const float* Wk    = (const float*)d_in[4];
    const float* bk    = (const float*)d_in[5];
    const float* Wv    = (const float*)d_in[6];
    const float* bv    = (const float*)d_in[7];
    float* out = (float*)d_out;

    char* ws = (char*)d_ws;
    size_t off = 0;
    auto take = [&](size_t bytes) { char* p = ws + off; off += bytes; return p; };
    unsigned short* Qh  = (unsigned short*)take(8192ull  * 1024 * 2);
    unsigned short* Ql  = (unsigned short*)take(8192ull  * 1024 * 2);
    unsigned short* Kh  = (unsigned short*)take(32768ull * 1024 * 2);
    unsigned short* Kl  = (unsigned short*)take(32768ull * 1024 * 2);
    unsigned short* Vh  = (unsigned short*)take(32768ull * 1024 * 2);
    unsigned short* WqH = (unsigned short*)take(1024ull * 1024 * 2);
    unsigned short* WqL = (unsigned short*)take(1024ull * 1024 * 2);
    unsigned short* WkH = (unsigned short*)take(1024ull * 1024 * 2);
    unsigned short* WkL = (unsigned short*)take(1024ull * 1024 * 2);
    unsigned short* WvH = (unsigned short*)take(1024ull * 1024 * 2);
    float*          S   = (float*)take(8ull * 1024 * 4096 * 4);
    (void)ws_size; (void)in_sizes; (void)n_in; (void)out_size;

    // 1. split weights into bf16 hi/lo planes (Wv: hi only)
    split_kernel<<<1024, 256, 0, stream>>>(Wq, WqH, WqL, 1024 * 1024);
    split_kernel<<<1024, 256, 0, stream>>>(Wk, WkH, WkL, 1024 * 1024);
    split_kernel<<<1024, 256, 0, stream>>>(Wv, WvH, nullptr, 1024 * 1024);

    // 2. projections (split-bf16 for Q,K; plain bf16 for V), biases fused
    gemm_kernel<true, 0, 0, 2, true><<<dim3(8, 64, 1), NT, 0, stream>>>(
        query, nullptr, nullptr, WqH, WqL, bq, nullptr, Qh, Ql,
        8192, 1024, 1024, 1024, 1024, 1024, 0, 0, 0);
    gemm_kernel<true, 0, 0, 2, true><<<dim3(8, 256, 1), NT, 0, stream>>>(
        ref, nullptr, nullptr, WkH, WkL, bk, nullptr, Kh, Kl,
        32768, 1024, 1024, 1024, 1024, 1024, 0, 0, 0);
    gemm_kernel<false, 0, 0, 1, true><<<dim3(8, 256, 1), NT, 0, stream>>>(
        ref, nullptr, nullptr, WvH, nullptr, bv, nullptr, Vh, nullptr,
        32768, 1024, 1024, 1024, 1024, 1024, 0, 0, 0);

    // 3. logits S = Q K^T (split-bf16, fp32 out), batched: K planes are [key][h] = [n][k] direct
    gemm_kernel<true, 1, 1, 0, false><<<dim3(32, 8, 8), NT, 0, stream>>>(
        nullptr, Qh, Ql, Kh, Kl, nullptr, S, nullptr, nullptr,
        1024, 4096, 1024, 1024, 1024, 4096,
        1048576LL, 4194304LL, 4194304LL);

    // 4. row softmax, in-place bf16 P over S (P row stride 8192 elems), * 1/32 folded
    softmax_kernel<<<8192, 256, 0, stream>>>(S, (unsigned short*)S);

    // 5. O = P V (plain bf16), V is [key][h] = [k][n] -> transpose-staged
    gemm_kernel<false, 1, 0, 0, false><<<dim3(8, 8, 8), NT, 0, stream>>>(
        nullptr, (unsigned short*)S, nullptr, Vh, nullptr, nullptr, out, nullptr, nullptr,
        1024, 1024, 4096, 8192, 1024, 1024,
        8388608LL, 4194304LL, 1048576LL);
}

// Round 2
// 1167.511 us; speedup vs baseline: 1.0390x; 1.0390x over previous
//
#include <hip/hip_runtime.h>

typedef __bf16 bf16x8 __attribute__((ext_vector_type(8)));
typedef float  f32x4  __attribute__((ext_vector_type(4)));
typedef unsigned short ushort_t;

__device__ __forceinline__ float bf2f(unsigned short h) {
    union { unsigned int u; float f; } c; c.u = ((unsigned int)h) << 16; return c.f;
}
// round-to-nearest-even fp32 -> bf16
__device__ __forceinline__ unsigned short f2bf(float x) {
    union { float f; unsigned int u; } c; c.f = x;
    unsigned int u = c.u + 0x7FFFu + ((c.u >> 16) & 1u);
    return (unsigned short)(u >> 16);
}

// async global->LDS, 16 B per lane; LDS dest = wave-uniform base + lane*16
typedef __attribute__((address_space(1))) void gvoid;
typedef __attribute__((address_space(3))) void lvoid;
__device__ __forceinline__ void g2l16(const ushort_t* g, ushort_t* l) {
    __builtin_amdgcn_global_load_lds((gvoid*)g, (lvoid*)l, 16, 0, 0);
}

#define BM 128
#define BN 128
#define BK 32
#define NT 256

// ---------- weight transpose+split: W[k][n] fp32 -> T[n][k] bf16 hi/lo ----------
__global__ void wsplit_kernel(const float* __restrict__ Wq, const float* __restrict__ Wk,
                              const float* __restrict__ Wv,
                              ushort_t* __restrict__ qh, ushort_t* __restrict__ ql,
                              ushort_t* __restrict__ kh, ushort_t* __restrict__ kl,
                              ushort_t* __restrict__ vh) {
    const int z = blockIdx.z;
    const float* W = (z == 0) ? Wq : (z == 1) ? Wk : Wv;
    ushort_t* th = (z == 0) ? qh : (z == 1) ? kh : vh;
    ushort_t* tl = (z == 0) ? ql : (z == 1) ? kl : nullptr;
    const int n = blockIdx.x * blockDim.x + threadIdx.x;   // grid.x=4, block=256
    for (int k0 = 0; k0 < 1024; k0 += 8) {
        union { ushort_t u[8]; uint4 v; } H, L;
        #pragma unroll
        for (int e = 0; e < 8; ++e) {
            float v = W[(long long)(k0 + e) * 1024 + n];   // coalesced across lanes
            H.u[e] = f2bf(v);
            L.u[e] = f2bf(v - bf2f(H.u[e]));
        }
        *(uint4*)&th[(long long)n * 1024 + k0] = H.v;      // per-lane contiguous 16B
        if (tl) *(uint4*)&tl[(long long)n * 1024 + k0] = L.v;
    }
}

// ---------- activation split: fp32 -> bf16 hi/lo planes ----------
__global__ void asplit_kernel(const float* __restrict__ x,
                              ushort_t* __restrict__ hi, ushort_t* __restrict__ lo, int n4) {
    int i = blockIdx.x * blockDim.x + threadIdx.x;
    if (i >= n4) return;
    float4 v = ((const float4*)x)[i];
    float vv[4] = {v.x, v.y, v.z, v.w};
    union { ushort_t u[4]; uint2 w; } H, L;
    #pragma unroll
    for (int e = 0; e < 4; ++e) {
        H.u[e] = f2bf(vv[e]);
        L.u[e] = f2bf(vv[e] - bf2f(H.u[e]));
    }
    ((uint2*)hi)[i] = H.w;
    ((uint2*)lo)[i] = L.w;
}

// ---------- unified GEMM: C[M,N] = A[m][k] * B[n][k]^T (+bias) ----------
// SPLIT: 3-MFMA split-bf16 (hi/lo planes of both operands)
// OUT_MODE: 0 = fp32 [m][n]; 2 = bf16 hi/lo planes [m][n]; 3 = bf16 transposed [n][m] batched by tM
template<bool SPLIT, int OUT_MODE, bool BIAS>
__global__ __launch_bounds__(NT, 2)
void gemm_kernel(const ushort_t* __restrict__ Ah, const ushort_t* __restrict__ Al,
                 const ushort_t* __restrict__ Bh, const ushort_t* __restrict__ Bl,
                 const float* __restrict__ bias,
                 float* __restrict__ Cf, ushort_t* __restrict__ Cb, ushort_t* __restrict__ Cl,
                 int K, int lda, int ldb, int ldc,
                 long long sA, long long sB, long long sC, int tM)
{
    __shared__ __align__(16) ushort_t AsH[BM * BK];
    __shared__ __align__(16) ushort_t BsH[BN * BK];
    __shared__ __align__(16) ushort_t AsL[SPLIT ? BM * BK : 8];
    __shared__ __align__(16) ushort_t BsL[SPLIT ? BN * BK : 8];
    __shared__ float biasS[BN];

    const int tid  = threadIdx.x;
    const int b    = blockIdx.z;
    const int m0   = blockIdx.y * BM;
    const int n0   = blockIdx.x * BN;
    const int lane = tid & 63;
    const int w    = tid >> 6;
    const int wm   = (w >> 1) * 64;
    const int wn   = (w & 1) * 64;
    const int l15  = lane & 15;
    const int quad = lane >> 4;

    if (BIAS && tid < BN) biasS[tid] = bias[n0 + tid];

    const long long aBase = (long long)b * sA + (long long)m0 * lda;
    const long long bBase = (long long)b * sB + (long long)n0 * ldb;

    f32x4 acc[4][4];
    #pragma unroll
    for (int i = 0; i < 4; ++i)
        #pragma unroll
        for (int j = 0; j < 4; ++j)
            #pragma unroll
            for (int r = 0; r < 4; ++r) acc[i][j][r] = 0.0f;

    for (int k0 = 0; k0 < K; k0 += BK) {
        __syncthreads();   // previous tile's frag reads done before overwrite
        #pragma unroll
        for (int p = 0; p < 2; ++p) {
            const int cc  = p * NT + tid;          // chunk id: 512 chunks of 8 bf16
            const int row = cc >> 2;
            const int col = (cc & 3) * 8;
            const int lds = (p * NT + (tid & ~63)) * 8;  // wave-uniform elem offset
            g2l16(Ah + aBase + (long long)row * lda + k0 + col, &AsH[lds]);
            g2l16(Bh + bBase + (long long)row * ldb + k0 + col, &BsH[lds]);
            if constexpr (SPLIT) {
                g2l16(Al + aBase + (long long)row * lda + k0 + col, &AsL[lds]);
                g2l16(Bl + bBase + (long long)row * ldb + k0 + col, &BsL[lds]);
            }
        }
        __syncthreads();   // drains vmcnt(0) + barrier

        bf16x8 ah[4], al[4], bh[4], bl[4];
        #pragma unroll
        for (int i = 0; i < 4; ++i) {
            const int r = wm + i * 16 + l15;
            ah[i] = *(const bf16x8*)&AsH[r * BK + quad * 8];
            if constexpr (SPLIT) al[i] = *(const bf16x8*)&AsL[r * BK + quad * 8];
        }
        #pragma unroll
        for (int j = 0; j < 4; ++j) {
            const int r = wn + j * 16 + l15;
            bh[j] = *(const bf16x8*)&BsH[r * BK + quad * 8];
            if constexpr (SPLIT) bl[j] = *(const bf16x8*)&BsL[r * BK + quad * 8];
        }
        #pragma unroll
        for (int i = 0; i < 4; ++i)
            #pragma unroll
            for (int j = 0; j < 4; ++j) {
                acc[i][j] = __builtin_amdgcn_mfma_f32_16x16x32_bf16(ah[i], bh[j], acc[i][j], 0, 0, 0);
                if constexpr (SPLIT) {
                    acc[i][j] = __builtin_amdgcn_mfma_f32_16x16x32_bf16(ah[i], bl[j], acc[i][j], 0, 0, 0);
                    acc[i][j] = __builtin_amdgcn_mfma_f32_16x16x32_bf16(al[i], bh[j], acc[i][j], 0, 0, 0);
                }
            }
    }

    // C/D layout: col = lane&15, row = quad*4 + r (m89-verified)
    #pragma unroll
    for (int i = 0; i < 4; ++i)
        #pragma unroll
        for (int j = 0; j < 4; ++j) {
            const int row0 = wm + i * 16 + quad * 4;
            const int col  = wn + j * 16 + l15;
            float c[4];
            #pragma unroll
            for (int r = 0; r < 4; ++r) {
                c[r] = acc[i][j][r];
                if (BIAS) c[r] += biasS[col];
            }
            if constexpr (OUT_MODE == 0) {
                #pragma unroll
                for (int r = 0; r < 4; ++r)
                    Cf[(long long)b * sC + (long long)(m0 + row0 + r) * ldc + (n0 + col)] = c[r];
            } else if constexpr (OUT_MODE == 2) {
                #pragma unroll
                for (int r = 0; r < 4; ++r) {
                    const long long o = (long long)b * sC + (long long)(m0 + row0 + r) * ldc + (n0 + col);
                    const ushort_t hh = f2bf(c[r]);
                    Cb[o] = hh;
                    Cl[o] = f2bf(c[r] - bf2f(hh));
                }
            } else {  // OUT_MODE == 3: transposed bf16, batched along m by tM
                const int mg  = m0 + row0;
                const int bb  = mg / tM;
                const int key = mg % tM;
                union { ushort_t u[4]; uint2 v; } P;
                #pragma unroll
                for (int r = 0; r < 4; ++r) P.u[r] = f2bf(c[r]);
                *(uint2*)&Cb[(long long)bb * sC + (long long)(n0 + col) * ldc + key] = P.v;
            }
        }
}

// ---------- row softmax: S fp32 [8192][4096] -> P bf16 in-place (row stride 8192) ----------
__global__ void softmax_kernel(float* __restrict__ S) {
    const int row = blockIdx.x;
    const int tid = threadIdx.x;
    float* s = S + (long long)row * 4096;
    float4 v[4];
    float m = -3.4e38f;
    #pragma unroll
    for (int i = 0; i < 4; ++i) {
        v[i] = ((const float4*)s)[tid + i * 256];
        m = fmaxf(fmaxf(fmaxf(m, v[i].x), fmaxf(v[i].y, v[i].z)), v[i].w);
    }
    __shared__ float red[256];
    red[tid] = m; __syncthreads();
    for (int st = 128; st > 0; st >>= 1) {
        if (tid < st) red[tid] = fmaxf(red[tid], red[tid + st]);
        __syncthreads();
    }
    m = red[0]; __syncthreads();
    float sum = 0.f;
    #pragma unroll
    for (int i = 0; i < 4; ++i) {
        v[i].x = __expf(v[i].x - m); v[i].y = __expf(v[i].y - m);
        v[i].z = __expf(v[i].z - m); v[i].w = __expf(v[i].w - m);
        sum += v[i].x + v[i].y + v[i].z + v[i].w;
    }
    red[tid] = sum; __syncthreads();
    for (int st = 128; st > 0; st >>= 1) {
        if (tid < st) red[tid] += red[tid + st];
        __syncthreads();
    }
    const float scale = 0.03125f / red[0];   // 1/sqrt(1024) post-softmax scale folded in
    ushort_t* p = (ushort_t*)S + (long long)row * 8192;
    #pragma unroll
    for (int i = 0; i < 4; ++i) {
        union { ushort_t u[4]; uint2 w; } P;
        P.u[0] = f2bf(v[i].x * scale); P.u[1] = f2bf(v[i].y * scale);
        P.u[2] = f2bf(v[i].z * scale); P.u[3] = f2bf(v[i].w * scale);
        ((uint2*)p)[tid + i * 256] = P.w;
    }
}

// ---------- launch ----------
extern "C" void kernel_launch(void* const* d_in, const int* in_sizes, int n_in,
                              void* d_out, int out_size, void* d_ws, size_t ws_size,
                              hipStream_t stream) {
    const float* query = (const float*)d_in[0];
    const float* ref   = (const float*)d_in[1];
    const float* Wq    = (const float*)d_in[2];
    const float* bq    = (const float*)d_in[3];
    const float* Wk    = (const float*)d_in[4];
    const float* bk    = (const float*)d_in[5];
    const float* Wv    = (const float*)d_in[6];
    const float* bv    = (const float*)d_in[7];
    float* out = (float*)d_out;
    (void)in_sizes; (void)n_in; (void)out_size; (void)ws_size;

    char* ws = (char*)d_ws;
    size_t off = 0;
    auto take = [&](size_t bytes) { char* p = ws + off; off += bytes; return p; };
    // region 0: activation planes (dead after projections) — S aliases this region
    ushort_t* Qah = (ushort_t*)take(16777216);   // 8192 x 1024
    ushort_t* Qal = (ushort_t*)take(16777216);
    ushort_t* Rl  = (ushort_t*)take(67108864);   // 32768 x 1024
    ushort_t* Rh  = (ushort_t*)take(67108864);
    // region 1: persistent intermediates
    ushort_t* Qh  = (ushort_t*)take(16777216);
    ushort_t* Ql  = (ushort_t*)take(16777216);
    ushort_t* Kh  = (ushort_t*)take(67108864);
    ushort_t* Kl  = (ushort_t*)take(67108864);
    ushort_t* Vt  = (ushort_t*)take(67108864);   // [b][h][key] transposed V
    ushort_t* WqTh = (ushort_t*)take(2097152);
    ushort_t* WqTl = (ushort_t*)take(2097152);
    ushort_t* WkTh = (ushort_t*)take(2097152);
    ushort_t* WkTl = (ushort_t*)take(2097152);
    ushort_t* WvTh = (ushort_t*)take(2097152);
    float* S = (float*)(ws + 0);                 // 134 MB, aliases Qah/Qal/Rl/part of Rh

    // 1. prep: weight transpose+split, activation split
    wsplit_kernel<<<dim3(4, 1, 3), 256, 0, stream>>>(Wq, Wk, Wv, WqTh, WqTl, WkTh, WkTl, WvTh);
    asplit_kernel<<<8192, 256, 0, stream>>>(query, Qah, Qal, 2097152);
    asplit_kernel<<<32768, 256, 0, stream>>>(ref, Rh, Rl, 8388608);

    // 2. projections
    gemm_kernel<true, 2, true><<<dim3(8, 64, 1), NT, 0, stream>>>(
        Qah, Qal, WqTh, WqTl, bq, nullptr, Qh, Ql,
        1024, 1024, 1024, 1024, 0, 0, 0, 0);
    gemm_kernel<true, 2, true><<<dim3(8, 256, 1), NT, 0, stream>>>(
        Rh, Rl, WkTh, WkTl, bk, nullptr, Kh, Kl,
        1024, 1024, 1024, 1024, 0, 0, 0, 0);
    gemm_kernel<false, 3, true><<<dim3(8, 256, 1), NT, 0, stream>>>(
        Rh, nullptr, WvTh, nullptr, bv, nullptr, Vt, nullptr,
        1024, 1024, 1024, 4096, 0, 0, 4194304LL, 4096);

    // 3. logits S = Q K^T (split, fp32 out)
    gemm_kernel<true, 0, false><<<dim3(32, 8, 8), NT, 0, stream>>>(
        Qh, Ql, Kh, Kl, nullptr, S, nullptr, nullptr,
        1024, 1024, 1024, 4096, 1048576LL, 4194304LL, 4194304LL, 0);

    // 4. softmax (in-place bf16 P, row stride 8192, *1/32 folded)
    softmax_kernel<<<8192, 256, 0, stream>>>(S);

    // 5. O = P V  (A = P [q][key] stride 8192, B = Vt [h][key] direct)
    gemm_kernel<false, 0, false><<<dim3(8, 8, 8), NT, 0, stream>>>(
        (const ushort_t*)S, nullptr, Vt, nullptr, nullptr, out, nullptr, nullptr,
        4096, 8192, 4096, 1024, 8388608LL, 4194304LL, 1048576LL, 0);
}

// Round 3
// 733.058 us; speedup vs baseline: 1.6547x; 1.5927x over previous
//
#include <hip/hip_runtime.h>

typedef _Float16 f16x8 __attribute__((ext_vector_type(8)));
typedef float    f32x4 __attribute__((ext_vector_type(4)));
typedef unsigned short ushort_t;

__device__ __forceinline__ ushort_t f2h(float x) {
    union { _Float16 h; ushort_t u; } c; c.h = (_Float16)x; return c.u;
}

// async global->LDS, 16 B per lane; LDS dest = wave-uniform base + lane*16
typedef __attribute__((address_space(1))) void gvoid;
typedef __attribute__((address_space(3))) void lvoid;
__device__ __forceinline__ void g2l16(const ushort_t* g, ushort_t* l) {
    __builtin_amdgcn_global_load_lds((gvoid*)g, (lvoid*)l, 16, 0, 0);
}

#define BM 128
#define BN 128
#define BK 32
#define NT 256

// ---------- weight transpose+convert: W[k][n] fp32 -> WT[n][k] fp16 ----------
__global__ void wconv_kernel(const float* __restrict__ Wq, const float* __restrict__ Wk,
                             const float* __restrict__ Wv,
                             ushort_t* __restrict__ tq, ushort_t* __restrict__ tk,
                             ushort_t* __restrict__ tv) {
    const int z = blockIdx.z;
    const float* W = (z == 0) ? Wq : (z == 1) ? Wk : Wv;
    ushort_t* T = (z == 0) ? tq : (z == 1) ? tk : tv;
    const int n  = blockIdx.x * blockDim.x + threadIdx.x;   // 0..1023
    const int kb = blockIdx.y * 128;                        // k range per block
    for (int k0 = kb; k0 < kb + 128; k0 += 8) {
        union { ushort_t u[8]; uint4 v; } H;
        #pragma unroll
        for (int e = 0; e < 8; ++e)
            H.u[e] = f2h(W[(long long)(k0 + e) * 1024 + n]);   // coalesced across lanes
        *(uint4*)&T[(long long)n * 1024 + k0] = H.v;           // per-lane contiguous 16B
    }
}

// ---------- activation convert: fp32 -> fp16 ----------
__global__ void aconv_kernel(const float* __restrict__ x, ushort_t* __restrict__ h, int n4) {
    int i = blockIdx.x * blockDim.x + threadIdx.x;
    if (i >= n4) return;
    float4 v = ((const float4*)x)[i];
    union { ushort_t u[4]; uint2 w; } H;
    H.u[0] = f2h(v.x); H.u[1] = f2h(v.y); H.u[2] = f2h(v.z); H.u[3] = f2h(v.w);
    ((uint2*)h)[i] = H.w;
}

// ---------- fp16 GEMM (m97 structure): C[M,N] = A[m][k] * B[n][k]^T (+bias) ----------
// OUT_MODE: 0 = fp32 [m][n]; 1 = fp16 [m][n]; 3 = fp16 transposed [n][m], batched along m by tM
template<int OUT_MODE, bool BIAS>
__global__ __launch_bounds__(NT, 2)
void gemm_kernel(const ushort_t* __restrict__ A, const ushort_t* __restrict__ B,
                 const float* __restrict__ bias,
                 float* __restrict__ Cf, ushort_t* __restrict__ Ch,
                 int K, int lda, int ldb, int ldc,
                 long long sA, long long sB, long long sC, int tM)
{
    __shared__ __align__(16) ushort_t As[BM * BK];
    __shared__ __align__(16) ushort_t Bs[BN * BK];
    __shared__ float biasS[BN];

    const int tid  = threadIdx.x;
    const int b    = blockIdx.z;
    const int m0   = blockIdx.y * BM;
    const int n0   = blockIdx.x * BN;
    const int lane = tid & 63;
    const int w    = tid >> 6;
    const int wm   = (w >> 1) * 64;
    const int wn   = (w & 1) * 64;
    const int l15  = lane & 15;
    const int quad = lane >> 4;

    if (BIAS && tid < BN) biasS[tid] = bias[n0 + tid];

    const long long aBase = (long long)b * sA + (long long)m0 * lda;
    const long long bBase = (long long)b * sB + (long long)n0 * ldb;

    f32x4 acc[4][4];
    #pragma unroll
    for (int i = 0; i < 4; ++i)
        #pragma unroll
        for (int j = 0; j < 4; ++j)
            #pragma unroll
            for (int r = 0; r < 4; ++r) acc[i][j][r] = 0.0f;

    for (int k0 = 0; k0 < K; k0 += BK) {
        __syncthreads();   // previous tile's frag reads done before overwrite
        {
            const int row = tid >> 2;            // 64 rows per 256 threads... 128 rows via 2 instrs
            const int col = (tid & 3) * 8;
            const int lds = (tid & ~63) * 8;     // wave-uniform elem offset
            g2l16(A + aBase + (long long)row * lda + k0 + col, &As[lds]);
            g2l16(B + bBase + (long long)row * ldb + k0 + col, &Bs[lds]);
            const int row2 = row + 64;
            const int lds2 = lds + NT * 8;
            g2l16(A + aBase + (long long)row2 * lda + k0 + col, &As[lds2]);
            g2l16(B + bBase + (long long)row2 * ldb + k0 + col, &Bs[lds2]);
        }
        __syncthreads();   // drains vmcnt(0) + barrier

        f16x8 af[4], bf[4];
        #pragma unroll
        for (int i = 0; i < 4; ++i)
            af[i] = *(const f16x8*)&As[(wm + i * 16 + l15) * BK + quad * 8];
        #pragma unroll
        for (int j = 0; j < 4; ++j)
            bf[j] = *(const f16x8*)&Bs[(wn + j * 16 + l15) * BK + quad * 8];
        #pragma unroll
        for (int i = 0; i < 4; ++i)
            #pragma unroll
            for (int j = 0; j < 4; ++j)
                acc[i][j] = __builtin_amdgcn_mfma_f32_16x16x32_f16(af[i], bf[j], acc[i][j], 0, 0, 0);
    }

    // C/D layout: col = lane&15, row = quad*4 + r (m89-verified)
    #pragma unroll
    for (int i = 0; i < 4; ++i)
        #pragma unroll
        for (int j = 0; j < 4; ++j) {
            const int row0 = wm + i * 16 + quad * 4;
            const int col  = wn + j * 16 + l15;
            float c[4];
            #pragma unroll
            for (int r = 0; r < 4; ++r) {
                c[r] = acc[i][j][r];
                if (BIAS) c[r] += biasS[col];
            }
            if constexpr (OUT_MODE == 0) {
                #pragma unroll
                for (int r = 0; r < 4; ++r)
                    Cf[(long long)b * sC + (long long)(m0 + row0 + r) * ldc + (n0 + col)] = c[r];
            } else if constexpr (OUT_MODE == 1) {
                #pragma unroll
                for (int r = 0; r < 4; ++r)
                    Ch[(long long)b * sC + (long long)(m0 + row0 + r) * ldc + (n0 + col)] = f2h(c[r]);
            } else {  // OUT_MODE == 3: transposed fp16 [n][m], batched along m by tM
                const int mg  = m0 + row0;
                const int bb  = mg / tM;
                const int key = mg % tM;
                union { ushort_t u[4]; uint2 v; } P;
                #pragma unroll
                for (int r = 0; r < 4; ++r) P.u[r] = f2h(c[r]);
                *(uint2*)&Ch[(long long)bb * sC + (long long)(n0 + col) * ldc + key] = P.v;
            }
        }
}

// ---------- row softmax: S fp32 [8192][4096] -> P fp16 [8192][4096] (*1/32 folded) ----------
__global__ void softmax_kernel(const float* __restrict__ S, ushort_t* __restrict__ P) {
    const int row  = blockIdx.x;
    const int tid  = threadIdx.x;
    const int lane = tid & 63;
    const int wid  = tid >> 6;
    const float* s = S + (long long)row * 4096;
    float4 v[4];
    float m = -3.4e38f;
    #pragma unroll
    for (int i = 0; i < 4; ++i) {
        v[i] = ((const float4*)s)[tid + i * 256];
        m = fmaxf(fmaxf(fmaxf(m, v[i].x), fmaxf(v[i].y, v[i].z)), v[i].w);
    }
    __shared__ float redm[4], reds[4];
    #pragma unroll
    for (int o = 32; o > 0; o >>= 1) m = fmaxf(m, __shfl_down(m, o));
    if (lane == 0) redm[wid] = m;
    __syncthreads();
    m = fmaxf(fmaxf(redm[0], redm[1]), fmaxf(redm[2], redm[3]));
    float sum = 0.f;
    #pragma unroll
    for (int i = 0; i < 4; ++i) {
        v[i].x = __expf(v[i].x - m); v[i].y = __expf(v[i].y - m);
        v[i].z = __expf(v[i].z - m); v[i].w = __expf(v[i].w - m);
        sum += v[i].x + v[i].y + v[i].z + v[i].w;
    }
    #pragma unroll
    for (int o = 32; o > 0; o >>= 1) sum += __shfl_down(sum, o);
    if (lane == 0) reds[wid] = sum;
    __syncthreads();
    sum = reds[0] + reds[1] + reds[2] + reds[3];
    const float scale = 0.03125f / sum;   // 1/sqrt(1024) post-softmax scale folded in
    ushort_t* p = P + (long long)row * 4096;
    #pragma unroll
    for (int i = 0; i < 4; ++i) {
        union { ushort_t u[4]; uint2 w; } Pk;
        Pk.u[0] = f2h(v[i].x * scale); Pk.u[1] = f2h(v[i].y * scale);
        Pk.u[2] = f2h(v[i].z * scale); Pk.u[3] = f2h(v[i].w * scale);
        ((uint2*)p)[tid + i * 256] = Pk.w;
    }
}

// ---------- launch ----------
extern "C" void kernel_launch(void* const* d_in, const int* in_sizes, int n_in,
                              void* d_out, int out_size, void* d_ws, size_t ws_size,
                              hipStream_t stream) {
    const float* query = (const float*)d_in[0];
    const float* ref   = (const float*)d_in[1];
    const float* Wq    = (const float*)d_in[2];
    const float* bq    = (const float*)d_in[3];
    const float* Wk    = (const float*)d_in[4];
    const float* bk    = (const float*)d_in[5];
    const float* Wv    = (const float*)d_in[6];
    const float* bv    = (const float*)d_in[7];
    float* out = (float*)d_out;
    (void)in_sizes; (void)n_in; (void)out_size; (void)ws_size;

    char* ws = (char*)d_ws;
    // S (fp32, 134 MB) aliases Qa+Ra (dead before scores writes S)
    float*    S   = (float*)ws;
    ushort_t* Qa  = (ushort_t*)ws;                            // 8192x1024 fp16 (16 MB)
    ushort_t* Ra  = (ushort_t*)(ws + 16777216);               // 32768x1024 fp16 (64 MB)
    ushort_t* Qp  = (ushort_t*)(ws + 134217728);              // Q fp16 (16 MB)
    ushort_t* Kp  = (ushort_t*)(ws + 150994944);              // K fp16 (64 MB)
    ushort_t* Vt  = (ushort_t*)(ws + 218103808);              // V^T [b][h][key] fp16 (64 MB)
    ushort_t* WqT = (ushort_t*)(ws + 282066944);              // 2 MB each
    ushort_t* WkT = (ushort_t*)(ws + 284164096);
    ushort_t* WvT = (ushort_t*)(ws + 286261248);
    ushort_t* P   = Kp;                                       // P aliases K (dead after scores)

    // 1. prep: weight transpose+convert, activation convert
    wconv_kernel<<<dim3(4, 8, 3), 256, 0, stream>>>(Wq, Wk, Wv, WqT, WkT, WvT);
    aconv_kernel<<<8192, 256, 0, stream>>>(query, Qa, 2097152);
    aconv_kernel<<<32768, 256, 0, stream>>>(ref, Ra, 8388608);

    // 2. projections (fp16, bias fused)
    gemm_kernel<1, true><<<dim3(8, 64, 1), NT, 0, stream>>>(
        Qa, WqT, bq, nullptr, Qp, 1024, 1024, 1024, 1024, 0, 0, 0, 0);
    gemm_kernel<1, true><<<dim3(8, 256, 1), NT, 0, stream>>>(
        Ra, WkT, bk, nullptr, Kp, 1024, 1024, 1024, 1024, 0, 0, 0, 0);
    gemm_kernel<3, true><<<dim3(8, 256, 1), NT, 0, stream>>>(
        Ra, WvT, bv, nullptr, Vt, 1024, 1024, 1024, 4096, 0, 0, 4194304LL, 4096);

    // 3. logits S = Q K^T (fp32 out)
    gemm_kernel<0, false><<<dim3(32, 8, 8), NT, 0, stream>>>(
        Qp, Kp, nullptr, S, nullptr, 1024, 1024, 1024, 4096,
        1048576LL, 4194304LL, 4194304LL, 0);

    // 4. softmax: S fp32 -> P fp16 (compact stride 4096, *1/32 folded)
    softmax_kernel<<<8192, 256, 0, stream>>>(S, P);

    // 5. O = P V  (A = P [q][key], B = Vt [h][key] direct)
    gemm_kernel<0, false><<<dim3(8, 8, 8), NT, 0, stream>>>(
        P, Vt, nullptr, out, nullptr, 4096, 4096, 4096, 1024,
        4194304LL, 4194304LL, 1048576LL, 0);
}